// Round 2
// baseline (343.764 us; speedup 1.0000x reference)
//
#include <hip/hip_runtime.h>
#include <stdint.h>

typedef unsigned short u16;
typedef __bf16  bf16x8 __attribute__((ext_vector_type(8)));
typedef float   f32x4  __attribute__((ext_vector_type(4)));

__device__ __forceinline__ u16 f2bf(float f) {
    union { float f; unsigned u; } c; c.f = f;
    unsigned r = c.u + 0x7fffu + ((c.u >> 16) & 1u);   // RNE, finite inputs
    return (u16)(r >> 16);
}
__device__ __forceinline__ float bf2f(u16 b) {
    union { unsigned u; float f; } c; c.u = ((unsigned)b) << 16; return c.f;
}

// async 16B global->LDS. Generic LDS ptr: low 32 bits are the LDS offset on gfx9+.
__device__ __forceinline__ void g2l16(const u16* g, u16* l) {
    __builtin_amdgcn_global_load_lds(
        (__attribute__((address_space(1))) void*)(uintptr_t)g,
        (__attribute__((address_space(3))) void*)(uint32_t)(uintptr_t)l,
        16, 0, 0);
}

// ---------------------------------------------------------------------------
// NT GEMM (bf16 in, fp32 acc): C[m,n] = sum_k A[m,k]*B[n,k] (+ bias[m]).
// A,B row-major bf16, ld == K. Output bf16 or fp32 per OUT_F32.
// 128x128 tile, BK=32, 256 threads = 4 waves (2x2), each wave 4x4 MFMA tiles.
// M,N multiples of 128; K multiple of 32.
// ---------------------------------------------------------------------------
template <bool HAS_BIAS, bool OUT_F32>
__global__ __launch_bounds__(256) void gemm_nt(
    const u16* __restrict__ A, const u16* __restrict__ B, void* __restrict__ C,
    const float* __restrict__ bias, int M, int N, int K,
    long sA, long sB, long sC)
{
    __shared__ __align__(16) u16 As[128 * 32];
    __shared__ __align__(16) u16 Bs[128 * 32];

    const int bz = blockIdx.z;
    const int m0 = blockIdx.y * 128;
    const int n0 = blockIdx.x * 128;
    const u16* Ab = A + (long)bz * sA;
    const u16* Bb = B + (long)bz * sB;

    const int t = threadIdx.x;
    const int w = t >> 6, lane = t & 63;
    const int wr = w >> 1, wc = w & 1;

    f32x4 acc[4][4];
    const f32x4 zero = {0.f, 0.f, 0.f, 0.f};
#pragma unroll
    for (int i = 0; i < 4; ++i)
#pragma unroll
        for (int j = 0; j < 4; ++j) acc[i][j] = zero;

    // staging: element offset e0 covers tile rows via lane-contiguous 16B chunks
    const int e0   = w * 512 + lane * 8;   // issue 0; issue 1 at +2048 elems (+64 rows)
    const int row0 = e0 >> 5;
    const int col0 = e0 & 31;

    const u16* ap = Ab + (long)(m0 + row0) * K + col0;
    const u16* bp = Bb + (long)(n0 + row0) * K + col0;
    const long rstep = (long)64 * K;

    u16* lA0 = &As[e0]; u16* lA1 = &As[e0 + 2048];
    u16* lB0 = &Bs[e0]; u16* lB1 = &Bs[e0 + 2048];

    const int fr = lane & 15;
    const int fk = (lane >> 4) * 8;
    const u16* fa0 = &As[(wr * 64 + fr) * 32 + fk];
    const u16* fb0 = &Bs[(wc * 64 + fr) * 32 + fk];

    for (int k0 = 0; k0 < K; k0 += 32) {
        g2l16(ap + k0,         lA0);
        g2l16(ap + k0 + rstep, lA1);
        g2l16(bp + k0,         lB0);
        g2l16(bp + k0 + rstep, lB1);
        __syncthreads();   // drains vmcnt before barrier

        bf16x8 af[4], bv[4];
#pragma unroll
        for (int mi = 0; mi < 4; ++mi) af[mi] = *(const bf16x8*)(fa0 + mi * (16 * 32));
#pragma unroll
        for (int ni = 0; ni < 4; ++ni) bv[ni] = *(const bf16x8*)(fb0 + ni * (16 * 32));
#pragma unroll
        for (int mi = 0; mi < 4; ++mi)
#pragma unroll
            for (int ni = 0; ni < 4; ++ni)
                acc[mi][ni] = __builtin_amdgcn_mfma_f32_16x16x32_bf16(
                    af[mi], bv[ni], acc[mi][ni], 0, 0, 0);
        __syncthreads();
    }

    // C/D layout (m89-verified): col = lane&15, row = (lane>>4)*4 + reg
    const int ccol  = n0 + wc * 64 + fr;
    const int crow0 = m0 + wr * 64 + (lane >> 4) * 4;
#pragma unroll
    for (int mi = 0; mi < 4; ++mi) {
#pragma unroll
        for (int r = 0; r < 4; ++r) {
            const int row = crow0 + mi * 16 + r;
            float bvs = HAS_BIAS ? bias[row] : 0.f;
#pragma unroll
            for (int ni = 0; ni < 4; ++ni) {
                const float v = acc[mi][ni][r] + bvs;
                const long idx = (long)bz * sC + (long)row * N + ccol + ni * 16;
                if (OUT_F32) ((float*)C)[idx] = v;
                else         ((u16*)C)[idx]   = f2bf(v);
            }
        }
    }
}

// ---------------------------------------------------------------------------
// x fp32 [b,512,1024] -> Xt bf16 [b,1024,512] (cast + transpose, 64x64 tiles)
// ---------------------------------------------------------------------------
__global__ __launch_bounds__(256) void cast_transpose_x(
    const float* __restrict__ in, u16* __restrict__ out)
{
    __shared__ u16 tile[64][65];
    const int bz = blockIdx.z;
    const float* ip = in  + (long)bz * (512 * 1024);
    u16*         op = out + (long)bz * (1024 * 512);
    const int c0 = blockIdx.x * 64;
    const int r0 = blockIdx.y * 64;
    const int tx = threadIdx.x;  // 64
    const int ty = threadIdx.y;  // 4
#pragma unroll
    for (int i = ty; i < 64; i += 4)
        tile[i][tx] = f2bf(ip[(long)(r0 + i) * 1024 + c0 + tx]);
    __syncthreads();
#pragma unroll
    for (int i = ty; i < 64; i += 4)
        op[(long)(c0 + i) * 512 + r0 + tx] = tile[tx][i];
}

// ---------------------------------------------------------------------------
// bf16 64x64 tiled transpose, per-batch [512,1024] -> [1024,512]
// ---------------------------------------------------------------------------
__global__ __launch_bounds__(256) void transpose_rc(
    const u16* __restrict__ in, u16* __restrict__ out, long sIn, long sOut)
{
    __shared__ u16 tile[64][65];
    const int bz = blockIdx.z;
    const u16* ip = in  + (long)bz * sIn;
    u16*       op = out + (long)bz * sOut;
    const int c0 = blockIdx.x * 64;
    const int r0 = blockIdx.y * 64;
    const int tx = threadIdx.x;  // 64
    const int ty = threadIdx.y;  // 4
#pragma unroll
    for (int i = ty; i < 64; i += 4)
        tile[i][tx] = ip[(long)(r0 + i) * 1024 + c0 + tx];
    __syncthreads();
#pragma unroll
    for (int i = ty; i < 64; i += 4)
        op[(long)(c0 + i) * 512 + r0 + tx] = tile[tx][i];
}

// ---------------------------------------------------------------------------
// weights: wA/wB/wV -> Wcat bf16 [1536,512]; wR -> wRb bf16 [512,512];
// bA/bB/bV -> bcat fp32 [1536]
// ---------------------------------------------------------------------------
__global__ __launch_bounds__(256) void cast_weights(
    const float* __restrict__ wA, const float* __restrict__ wB,
    const float* __restrict__ wV, const float* __restrict__ wR,
    const float* __restrict__ bA, const float* __restrict__ bB,
    const float* __restrict__ bV,
    u16* __restrict__ Wcat, u16* __restrict__ wRb, float* __restrict__ bcat)
{
    const int tid = blockIdx.x * 256 + threadIdx.x;
    if (tid < 786432) {
        const int wsel = tid >> 18, off = tid & 262143;
        const float* src = (wsel == 0) ? wA : (wsel == 1) ? wB : wV;
        Wcat[tid] = f2bf(src[off]);
    } else if (tid < 1048576) {
        wRb[tid - 786432] = f2bf(wR[tid - 786432]);
    } else if (tid < 1048576 + 1536) {
        const int j = tid - 1048576;
        bcat[j] = (j < 512) ? bA[j] : (j < 1024) ? bB[j - 512] : bV[j - 1024];
    }
}

// ---------------------------------------------------------------------------
// Row softmax (in place, bf16) over rows 512..1535 of each batch's [1536,1024] Y
// ---------------------------------------------------------------------------
__global__ __launch_bounds__(256) void softmax_rows(u16* __restrict__ Y)
{
    u16* row = Y + (long)blockIdx.y * (1536 * 1024) + (long)(512 + blockIdx.x) * 1024;
    const int t = threadIdx.x;
    ushort4 u = ((const ushort4*)row)[t];
    float v0 = bf2f(u.x), v1 = bf2f(u.y), v2 = bf2f(u.z), v3 = bf2f(u.w);

    float m = fmaxf(fmaxf(v0, v1), fmaxf(v2, v3));
#pragma unroll
    for (int off = 32; off > 0; off >>= 1) m = fmaxf(m, __shfl_down(m, off));

    __shared__ float smax[4];
    __shared__ float ssum[4];
    const int w = t >> 6, lane = t & 63;
    if (lane == 0) smax[w] = m;
    __syncthreads();
    m = fmaxf(fmaxf(smax[0], smax[1]), fmaxf(smax[2], smax[3]));

    float e0 = __expf(v0 - m), e1 = __expf(v1 - m);
    float e2 = __expf(v2 - m), e3 = __expf(v3 - m);
    float s = e0 + e1 + e2 + e3;
#pragma unroll
    for (int off = 32; off > 0; off >>= 1) s += __shfl_down(s, off);
    if (lane == 0) ssum[w] = s;
    __syncthreads();
    const float inv = 1.0f / (ssum[0] + ssum[1] + ssum[2] + ssum[3]);

    ushort4 o;
    o.x = f2bf(e0 * inv); o.y = f2bf(e1 * inv);
    o.z = f2bf(e2 * inv); o.w = f2bf(e3 * inv);
    ((ushort4*)row)[t] = o;
}

// ---------------------------------------------------------------------------
extern "C" void kernel_launch(void* const* d_in, const int* in_sizes, int n_in,
                              void* d_out, int out_size, void* d_ws, size_t ws_size,
                              hipStream_t stream)
{
    (void)in_sizes; (void)n_in; (void)out_size; (void)ws_size;
    const float* x  = (const float*)d_in[0];
    const float* wA = (const float*)d_in[1];
    const float* bA = (const float*)d_in[2];
    const float* wB = (const float*)d_in[3];
    const float* bB = (const float*)d_in[4];
    const float* wV = (const float*)d_in[5];
    const float* bV = (const float*)d_in[6];
    const float* wR = (const float*)d_in[7];
    const float* bR = (const float*)d_in[8];
    float* out = (float*)d_out;

    const int B = 32;
    const long sY = (long)1536 * 1024;   // per-batch Y stride (bf16 elems)

    // workspace carve-up (~114 MB)
    char* p = (char*)d_ws;
    u16*   Y    = (u16*)p;   p += (long)B * sY * 2;          // 96 MB  [A;Bm;Vm]
    u16*   Gt   = (u16*)p;   p += (long)B * 512 * 512 * 2;   // 16 MB  G^T [d,c]
    u16*   Wcat = (u16*)p;   p += (long)1536 * 512 * 2;      // 1.5 MB
    u16*   wRb  = (u16*)p;   p += (long)512 * 512 * 2;       // 0.5 MB
    float* bcat = (float*)p; p += 1536 * 4;

    // Xt (bf16 [b,1024,512], 32 MB) lives in d_out — dead before GEMM7 writes out
    u16* Xt = (u16*)d_out;
    // After GEMM5: Vt reuses Y's A-region; after that G2 reuses Y's Bm-region
    u16* Vt = Y;                        // [1024,512] per batch, stride sY
    u16* G2 = Y + (long)512 * 1024;     // [512,512]  per batch, stride sY

    // 0. casts
    cast_transpose_x<<<dim3(16, 8, B), dim3(64, 4), 0, stream>>>(x, Xt);
    cast_weights<<<dim3(4103), 256, 0, stream>>>(wA, wB, wV, wR, bA, bB, bV,
                                                 Wcat, wRb, bcat);

    // 1. Y[b] = Wcat * X[b] + bcat   (NT: A=Wcat[1536,512], B=Xt[1024,512])
    gemm_nt<true, false><<<dim3(8, 12, B), 256, 0, stream>>>(
        Wcat, Xt, Y, bcat, 1536, 1024, 512, 0, (long)1024 * 512, sY);

    // 2. softmax over spatial for Bm and Vm rows (in place)
    softmax_rows<<<dim3(1024, B), 256, 0, stream>>>(Y);

    // 3. Gt[b][d,c] = sum_n attnM[d,n] * A[c,n]   (NT, K=1024)
    gemm_nt<false, false><<<dim3(4, 4, B), 256, 0, stream>>>(
        Y + (long)512 * 1024, Y, Gt, nullptr, 512, 512, 1024,
        sY, sY, (long)512 * 512);

    // 4. Vt[b] = attnV[b]^T  (A-region of Y is dead now)
    transpose_rc<<<dim3(16, 8, B), dim3(64, 4), 0, stream>>>(
        Y + (long)1024 * 1024, Vt, sY, sY);

    // 5. G2[b][o,d] = sum_c wR[o,c] * Gt[d,c]   (NT, K=512; Bm-region dead)
    gemm_nt<false, false><<<dim3(4, 4, B), 256, 0, stream>>>(
        wRb, Gt, G2, nullptr, 512, 512, 512, 0, (long)512 * 512, sY);

    // 6. out[b][o,n] = sum_d G2[o,d] * Vt[n,d] + bR[o]   (NT, K=512, fp32 out)
    gemm_nt<true, true><<<dim3(8, 4, B), 256, 0, stream>>>(
        G2, Vt, out, bR, 512, 1024, 512, sY, sY, (long)512 * 1024);
}

// Round 3
// 330.540 us; speedup vs baseline: 1.0400x; 1.0400x over previous
//
#include <hip/hip_runtime.h>
#include <stdint.h>

typedef unsigned short u16;
typedef __bf16  bf16x8 __attribute__((ext_vector_type(8)));
typedef float   f32x4  __attribute__((ext_vector_type(4)));

__device__ __forceinline__ u16 f2bf(float f) {
    union { float f; unsigned u; } c; c.f = f;
    unsigned r = c.u + 0x7fffu + ((c.u >> 16) & 1u);   // RNE, finite inputs
    return (u16)(r >> 16);
}
__device__ __forceinline__ float bf2f(u16 b) {
    union { unsigned u; float f; } c; c.u = ((unsigned)b) << 16; return c.f;
}

// async 16B global->LDS. Generic LDS ptr: low 32 bits are the LDS offset on gfx9+.
__device__ __forceinline__ void g2l16(const u16* g, u16* l) {
    __builtin_amdgcn_global_load_lds(
        (__attribute__((address_space(1))) void*)(uintptr_t)g,
        (__attribute__((address_space(3))) void*)(uint32_t)(uintptr_t)l,
        16, 0, 0);
}

// ---------------------------------------------------------------------------
// NT GEMM (bf16 in, fp32 acc): C[m,n] = sum_k A[m,k]*B[n,k] (+ bias[m]).
// A,B row-major bf16, ld == K. Output bf16 or fp32 per OUT_F32.
// 128x128 tile, BK=64, 256 threads = 4 waves (2x2), each wave 4x4 MFMA tiles.
// LDS XOR-swizzle: physical 16B chunk = logical ^ (row&7) -> 2-way (free)
// bank aliasing on ds_read_b128 instead of 8/16-way.
// M,N multiples of 128; K multiple of 64.
// ---------------------------------------------------------------------------
template <bool HAS_BIAS, bool OUT_F32>
__global__ __launch_bounds__(256) void gemm_nt(
    const u16* __restrict__ A, const u16* __restrict__ B, void* __restrict__ C,
    const float* __restrict__ bias, int M, int N, int K,
    long sA, long sB, long sC)
{
    __shared__ __align__(16) u16 As[128 * 64];
    __shared__ __align__(16) u16 Bs[128 * 64];

    const int bz = blockIdx.z;
    const int m0 = blockIdx.y * 128;
    const int n0 = blockIdx.x * 128;
    const u16* Ab = A + (long)bz * sA;
    const u16* Bb = B + (long)bz * sB;

    const int t = threadIdx.x;
    const int w = t >> 6, lane = t & 63;
    const int wr = w >> 1, wc = w & 1;

    f32x4 acc[4][4];
    const f32x4 zero = {0.f, 0.f, 0.f, 0.f};
#pragma unroll
    for (int i = 0; i < 4; ++i)
#pragma unroll
        for (int j = 0; j < 4; ++j) acc[i][j] = zero;

    // Staging: 16B-slot s covers LDS [row][phys_chunk]; the global source
    // column is swizzled so phys = logical ^ (row&7).
    int  sOff[4];
    long aoff[4], boff[4];
#pragma unroll
    for (int i = 0; i < 4; ++i) {
        const int s   = i * 256 + w * 64 + lane;     // 16B slot, 0..1023
        const int row = s >> 3;
        const int col = ((s & 7) ^ (row & 7)) * 8;   // element col in [0,64)
        sOff[i] = s * 8;                             // element offset in LDS
        aoff[i] = (long)(m0 + row) * K + col;
        boff[i] = (long)(n0 + row) * K + col;
    }

    // Fragment read offsets (swizzled): lane reads logical chunk (kh*4+q) of
    // row fr -> physical chunk ((kh*4+q) ^ (fr&7)).
    const int fr = lane & 15;
    const int q  = lane >> 4;
    const int o0 = ((q ^ (fr & 7)) * 8);   // kh=0; kh=1 is o0 ^ 32
    const u16* fa = &As[(wr * 64 + fr) * 64];
    const u16* fb = &Bs[(wc * 64 + fr) * 64];

    for (int k0 = 0; k0 < K; k0 += 64) {
#pragma unroll
        for (int i = 0; i < 4; ++i) g2l16(Ab + aoff[i] + k0, &As[sOff[i]]);
#pragma unroll
        for (int i = 0; i < 4; ++i) g2l16(Bb + boff[i] + k0, &Bs[sOff[i]]);
        __syncthreads();   // drains vmcnt before barrier

#pragma unroll
        for (int kh = 0; kh < 2; ++kh) {
            const int o = o0 ^ (kh * 32);
            bf16x8 af[4], bv[4];
#pragma unroll
            for (int mi = 0; mi < 4; ++mi) af[mi] = *(const bf16x8*)(fa + mi * 1024 + o);
#pragma unroll
            for (int ni = 0; ni < 4; ++ni) bv[ni] = *(const bf16x8*)(fb + ni * 1024 + o);
#pragma unroll
            for (int mi = 0; mi < 4; ++mi)
#pragma unroll
                for (int ni = 0; ni < 4; ++ni)
                    acc[mi][ni] = __builtin_amdgcn_mfma_f32_16x16x32_bf16(
                        af[mi], bv[ni], acc[mi][ni], 0, 0, 0);
        }
        __syncthreads();
    }

    // C/D layout (m89-verified): col = lane&15, row = (lane>>4)*4 + reg
    const int ccol  = n0 + wc * 64 + fr;
    const int crow0 = m0 + wr * 64 + (lane >> 4) * 4;
#pragma unroll
    for (int mi = 0; mi < 4; ++mi) {
#pragma unroll
        for (int r = 0; r < 4; ++r) {
            const int row = crow0 + mi * 16 + r;
            float bvs = HAS_BIAS ? bias[row] : 0.f;
#pragma unroll
            for (int ni = 0; ni < 4; ++ni) {
                const float v = acc[mi][ni][r] + bvs;
                const long idx = (long)bz * sC + (long)row * N + ccol + ni * 16;
                if (OUT_F32) ((float*)C)[idx] = v;
                else         ((u16*)C)[idx]   = f2bf(v);
            }
        }
    }
}

// ---------------------------------------------------------------------------
// x fp32 [b,512,1024] -> Xt bf16 [b,1024,512] (cast + transpose, 64x64 tiles)
// ---------------------------------------------------------------------------
__global__ __launch_bounds__(256) void cast_transpose_x(
    const float* __restrict__ in, u16* __restrict__ out)
{
    __shared__ u16 tile[64][65];
    const int bz = blockIdx.z;
    const float* ip = in  + (long)bz * (512 * 1024);
    u16*         op = out + (long)bz * (1024 * 512);
    const int c0 = blockIdx.x * 64;
    const int r0 = blockIdx.y * 64;
    const int tx = threadIdx.x;  // 64
    const int ty = threadIdx.y;  // 4
#pragma unroll
    for (int i = ty; i < 64; i += 4)
        tile[i][tx] = f2bf(ip[(long)(r0 + i) * 1024 + c0 + tx]);
    __syncthreads();
#pragma unroll
    for (int i = ty; i < 64; i += 4)
        op[(long)(c0 + i) * 512 + r0 + tx] = tile[tx][i];
}

// ---------------------------------------------------------------------------
// bf16 64x64 tiled transpose, per-batch [512,1024] -> [1024,512]
// ---------------------------------------------------------------------------
__global__ __launch_bounds__(256) void transpose_rc(
    const u16* __restrict__ in, u16* __restrict__ out, long sIn, long sOut)
{
    __shared__ u16 tile[64][65];
    const int bz = blockIdx.z;
    const u16* ip = in  + (long)bz * sIn;
    u16*       op = out + (long)bz * sOut;
    const int c0 = blockIdx.x * 64;
    const int r0 = blockIdx.y * 64;
    const int tx = threadIdx.x;  // 64
    const int ty = threadIdx.y;  // 4
#pragma unroll
    for (int i = ty; i < 64; i += 4)
        tile[i][tx] = ip[(long)(r0 + i) * 1024 + c0 + tx];
    __syncthreads();
#pragma unroll
    for (int i = ty; i < 64; i += 4)
        op[(long)(c0 + i) * 512 + r0 + tx] = tile[tx][i];
}

// ---------------------------------------------------------------------------
// weights: wA/wB/wV -> Wcat bf16 [1536,512]; wR -> wRb bf16 [512,512];
// bA/bB/bV -> bcat fp32 [1536]
// ---------------------------------------------------------------------------
__global__ __launch_bounds__(256) void cast_weights(
    const float* __restrict__ wA, const float* __restrict__ wB,
    const float* __restrict__ wV, const float* __restrict__ wR,
    const float* __restrict__ bA, const float* __restrict__ bB,
    const float* __restrict__ bV,
    u16* __restrict__ Wcat, u16* __restrict__ wRb, float* __restrict__ bcat)
{
    const int tid = blockIdx.x * 256 + threadIdx.x;
    if (tid < 786432) {
        const int wsel = tid >> 18, off = tid & 262143;
        const float* src = (wsel == 0) ? wA : (wsel == 1) ? wB : wV;
        Wcat[tid] = f2bf(src[off]);
    } else if (tid < 1048576) {
        wRb[tid - 786432] = f2bf(wR[tid - 786432]);
    } else if (tid < 1048576 + 1536) {
        const int j = tid - 1048576;
        bcat[j] = (j < 512) ? bA[j] : (j < 1024) ? bB[j - 512] : bV[j - 1024];
    }
}

// ---------------------------------------------------------------------------
// Row softmax (in place, bf16) over rows 512..1535 of each batch's [1536,1024] Y
// ---------------------------------------------------------------------------
__global__ __launch_bounds__(256) void softmax_rows(u16* __restrict__ Y)
{
    u16* row = Y + (long)blockIdx.y * (1536 * 1024) + (long)(512 + blockIdx.x) * 1024;
    const int t = threadIdx.x;
    ushort4 u = ((const ushort4*)row)[t];
    float v0 = bf2f(u.x), v1 = bf2f(u.y), v2 = bf2f(u.z), v3 = bf2f(u.w);

    float m = fmaxf(fmaxf(v0, v1), fmaxf(v2, v3));
#pragma unroll
    for (int off = 32; off > 0; off >>= 1) m = fmaxf(m, __shfl_down(m, off));

    __shared__ float smax[4];
    __shared__ float ssum[4];
    const int w = t >> 6, lane = t & 63;
    if (lane == 0) smax[w] = m;
    __syncthreads();
    m = fmaxf(fmaxf(smax[0], smax[1]), fmaxf(smax[2], smax[3]));

    float e0 = __expf(v0 - m), e1 = __expf(v1 - m);
    float e2 = __expf(v2 - m), e3 = __expf(v3 - m);
    float s = e0 + e1 + e2 + e3;
#pragma unroll
    for (int off = 32; off > 0; off >>= 1) s += __shfl_down(s, off);
    if (lane == 0) ssum[w] = s;
    __syncthreads();
    const float inv = 1.0f / (ssum[0] + ssum[1] + ssum[2] + ssum[3]);

    ushort4 o;
    o.x = f2bf(e0 * inv); o.y = f2bf(e1 * inv);
    o.z = f2bf(e2 * inv); o.w = f2bf(e3 * inv);
    ((ushort4*)row)[t] = o;
}

// ---------------------------------------------------------------------------
extern "C" void kernel_launch(void* const* d_in, const int* in_sizes, int n_in,
                              void* d_out, int out_size, void* d_ws, size_t ws_size,
                              hipStream_t stream)
{
    (void)in_sizes; (void)n_in; (void)out_size; (void)ws_size;
    const float* x  = (const float*)d_in[0];
    const float* wA = (const float*)d_in[1];
    const float* bA = (const float*)d_in[2];
    const float* wB = (const float*)d_in[3];
    const float* bB = (const float*)d_in[4];
    const float* wV = (const float*)d_in[5];
    const float* bV = (const float*)d_in[6];
    const float* wR = (const float*)d_in[7];
    const float* bR = (const float*)d_in[8];
    float* out = (float*)d_out;

    const int B = 32;
    const long sY = (long)1536 * 1024;   // per-batch Y stride (bf16 elems)

    // workspace carve-up (~114 MB)
    char* p = (char*)d_ws;
    u16*   Y    = (u16*)p;   p += (long)B * sY * 2;          // 96 MB  [A;Bm;Vm]
    u16*   Gt   = (u16*)p;   p += (long)B * 512 * 512 * 2;   // 16 MB  G^T [d,c]
    u16*   Wcat = (u16*)p;   p += (long)1536 * 512 * 2;      // 1.5 MB
    u16*   wRb  = (u16*)p;   p += (long)512 * 512 * 2;       // 0.5 MB
    float* bcat = (float*)p; p += 1536 * 4;

    // Xt (bf16 [b,1024,512], 32 MB) lives in d_out — dead before GEMM6 writes out
    u16* Xt = (u16*)d_out;
    // After GEMM3: Vt reuses Y's A-region; G2 reuses Y's Bm-region
    u16* Vt = Y;                        // [1024,512] per batch, stride sY
    u16* G2 = Y + (long)512 * 1024;     // [512,512]  per batch, stride sY

    // 0. casts
    cast_transpose_x<<<dim3(16, 8, B), dim3(64, 4), 0, stream>>>(x, Xt);
    cast_weights<<<dim3(4103), 256, 0, stream>>>(wA, wB, wV, wR, bA, bB, bV,
                                                 Wcat, wRb, bcat);

    // 1. Y[b] = Wcat * X[b] + bcat   (NT: A=Wcat[1536,512], B=Xt[1024,512])
    gemm_nt<true, false><<<dim3(8, 12, B), 256, 0, stream>>>(
        Wcat, Xt, Y, bcat, 1536, 1024, 512, 0, (long)1024 * 512, sY);

    // 2. softmax over spatial for Bm and Vm rows (in place)
    softmax_rows<<<dim3(1024, B), 256, 0, stream>>>(Y);

    // 3. Gt[b][d,c] = sum_n attnM[d,n] * A[c,n]   (NT, K=1024)
    gemm_nt<false, false><<<dim3(4, 4, B), 256, 0, stream>>>(
        Y + (long)512 * 1024, Y, Gt, nullptr, 512, 512, 1024,
        sY, sY, (long)512 * 512);

    // 4. Vt[b] = attnV[b]^T  (A-region of Y is dead now)
    transpose_rc<<<dim3(16, 8, B), dim3(64, 4), 0, stream>>>(
        Y + (long)1024 * 1024, Vt, sY, sY);

    // 5. G2[b][o,d] = sum_c wR[o,c] * Gt[d,c]   (NT, K=512; Bm-region dead)
    gemm_nt<false, false><<<dim3(4, 4, B), 256, 0, stream>>>(
        wRb, Gt, G2, nullptr, 512, 512, 512, 0, (long)512 * 512, sY);

    // 6. out[b][o,n] = sum_d G2[o,d] * Vt[n,d] + bR[o]   (NT, K=512, fp32 out)
    gemm_nt<true, true><<<dim3(8, 4, B), 256, 0, stream>>>(
        G2, Vt, out, bR, 512, 1024, 512, sY, sY, (long)512 * 1024);
}